// Round 4
// baseline (59.541 us; speedup 1.0000x reference)
//
#include <hip/hip_runtime.h>
#include <math.h>

#define GRID_G 16
#define K_SLOPE 10.0f
#define LOG2E 1.4426950408889634f
#define GAP_SKIP 4.5f      // AABB-gap above which IoU <= 4e-6 (proven bound)
#define SPLIT2 16          // threads per close pair in phase 2 (one gy row each)
#define P2_BLOCKS 2048

// ---------------- phase 1: classify pairs, compact close ones ----------------
__global__ __launch_bounds__(256) void classify_kernel(
    const float* __restrict__ P, const float* __restrict__ T,
    float* __restrict__ out, unsigned int* __restrict__ count,
    unsigned int* __restrict__ list, int N, int M)
{
    int pair = blockIdx.x * 256 + threadIdx.x;
    if (pair >= N * M) return;
    int i = pair / M, j = pair - i * M;

    float cxp = P[5*i+0], cyp = P[5*i+1], wp = P[5*i+2], hp = P[5*i+3], thp = P[5*i+4];
    float cxt = T[5*j+0], cyt = T[5*j+1], wt = T[5*j+2], ht = T[5*j+3], tht = T[5*j+4];

    float sp, cp, st, ct;
    __sincosf(thp, &sp, &cp);    // fast trig: threshold has >1px slack
    __sincosf(tht, &st, &ct);

    float hwp = 0.5f * (wp * fabsf(cp) + hp * fabsf(sp));
    float hhp = 0.5f * (wp * fabsf(sp) + hp * fabsf(cp));
    float hwt = 0.5f * (wt * fabsf(ct) + ht * fabsf(st));
    float hht = 0.5f * (wt * fabsf(st) + ht * fabsf(ct));

    float gx = fmaxf(0.f, fabsf(cxp - cxt) - (hwp + hwt));
    float gy = fmaxf(0.f, fabsf(cyp - cyt) - (hhp + hht));
    bool close = (gx*gx + gy*gy <= GAP_SKIP * GAP_SKIP);

    unsigned long long mask = __ballot(close);
    if (mask) {
        int lane = threadIdx.x & 63;
        int leader = __ffsll(mask) - 1;
        unsigned int base = 0;
        if (lane == leader)
            base = atomicAdd(count, (unsigned int)__popcll(mask));
        base = __shfl(base, leader);
        if (close) {
            unsigned int off = (unsigned int)__popcll(mask & ((1ull << lane) - 1ull));
            list[base + off] = (unsigned int)pair;
        }
    }
    if (!close) out[pair] = 0.0f;
}

// ---------------- phase 2: full PIoU on close pairs only ----------------
__global__ __launch_bounds__(256) void piou_close_kernel(
    const float* __restrict__ P, const float* __restrict__ T,
    float* __restrict__ out, const unsigned int* __restrict__ count,
    const unsigned int* __restrict__ list, int M)
{
    unsigned int n = *count;
    unsigned int items = n * SPLIT2;
    unsigned int tid = blockIdx.x * 256 + threadIdx.x;
    const unsigned int stride = P2_BLOCKS * 256;

    const float K2 = K_SLOPE * LOG2E;
    const float inv_g = 1.0f / (float)GRID_G;

    for (unsigned int it = tid; it < items; it += stride) {
        unsigned int pair = list[it >> 4];
        int sub = (int)(it & 15);          // gy row
        int i = pair / (unsigned int)M, j = pair - i * (unsigned int)M;

        float cxp = P[5*i+0], cyp = P[5*i+1], wp = P[5*i+2], hp = P[5*i+3], thp = P[5*i+4];
        float cxt = T[5*j+0], cyt = T[5*j+1], wt = T[5*j+2], ht = T[5*j+3], tht = T[5*j+4];

        float sp, cp, st, ct;
        sincosf(thp, &sp, &cp);            // precise: feeds the actual values
        sincosf(tht, &st, &ct);

        float acp = fabsf(cp), asp = fabsf(sp);
        float hwp = 0.5f * (wp * acp + hp * asp);
        float hhp = 0.5f * (wp * asp + hp * acp);
        float act = fabsf(ct), ast = fabsf(st);
        float hwt = 0.5f * (wt * act + ht * ast);
        float hht = 0.5f * (wt * ast + ht * act);

        float xmin = fminf(cxp - hwp, cxt - hwt);
        float xmax = fmaxf(cxp + hwp, cxt + hwt);
        float ymin = fminf(cyp - hhp, cyt - hht);
        float ymax = fmaxf(cyp + hhp, cyt + hht);

        float dxr = xmax - xmin;
        float dyr = ymax - ymin;
        float stepx = dxr * inv_g;

        float cwp = -0.5f * K2 * wp;
        float chp = -0.5f * K2 * hp;
        float cwt = -0.5f * K2 * wt;
        float cht = -0.5f * K2 * ht;

        float iw1 = stepx * cp, ih1 = -stepx * sp;
        float iw2 = stepx * ct, ih2 = -stepx * st;

        float px0 = fmaf(dxr, 0.5f * inv_g, xmin);
        float dxp = px0 - cxp, dxt = px0 - cxt;

        float py  = fmaf(dyr, ((float)sub + 0.5f) * inv_g, ymin);
        float dyp = py - cyp, dyt = py - cyt;

        float rw1_0 =  dxp * cp + dyp * sp;
        float rh1_0 = -dxp * sp + dyp * cp;
        float rw2_0 =  dxt * ct + dyt * st;
        float rh2_0 = -dxt * st + dyt * ct;

        float s1 = 0.f, s2 = 0.f, s12 = 0.f;

        #pragma unroll
        for (int gx = 0; gx < GRID_G; ++gx) {
            float g = (float)gx;
            float rw1 = fmaf(g, iw1, rw1_0);
            float rh1 = fmaf(g, ih1, rh1_0);
            float rw2 = fmaf(g, iw2, rw2_0);
            float rh2 = fmaf(g, ih2, rh2_0);

            float ea1 = __builtin_amdgcn_exp2f(fmaf(K2, fabsf(rw1), cwp));
            float eb1 = __builtin_amdgcn_exp2f(fmaf(K2, fabsf(rh1), chp));
            float ea2 = __builtin_amdgcn_exp2f(fmaf(K2, fabsf(rw2), cwt));
            float eb2 = __builtin_amdgcn_exp2f(fmaf(K2, fabsf(rh2), cht));

            float d1 = (1.0f + ea1) * (1.0f + eb1);
            float d2 = (1.0f + ea2) * (1.0f + eb2);
            float r1 = __builtin_amdgcn_rcpf(d1);
            float r2 = __builtin_amdgcn_rcpf(d2);

            s1  += r1;
            s2  += r2;
            s12  = fmaf(r1, r2, s12);
        }

        // combine the 16 row-partials (lanes of same pair are 16 consecutive lanes)
        #pragma unroll
        for (int m = 1; m < SPLIT2; m <<= 1) {
            s1  += __shfl_xor(s1,  m);
            s2  += __shfl_xor(s2,  m);
            s12 += __shfl_xor(s12, m);
        }

        if (sub == 0)
            out[pair] = s12 / (s1 + s2 - s12 + 1e-6f);
    }
}

// ---------------- fallback: monolithic (round-1) kernel ----------------
__global__ __launch_bounds__(256) void piou_pairwise_kernel(
    const float* __restrict__ P, const float* __restrict__ T,
    float* __restrict__ out, int N, int M)
{
    int gtid = blockIdx.x * blockDim.x + threadIdx.x;
    int pair = gtid >> 2;
    int sub  = gtid & 3;
    if (pair >= N * M) return;
    int i = pair / M, j = pair - i * M;

    float cxp = P[5*i+0], cyp = P[5*i+1], wp = P[5*i+2], hp = P[5*i+3], thp = P[5*i+4];
    float cxt = T[5*j+0], cyt = T[5*j+1], wt = T[5*j+2], ht = T[5*j+3], tht = T[5*j+4];

    float sp, cp, st, ct;
    sincosf(thp, &sp, &cp);
    sincosf(tht, &st, &ct);

    float acp = fabsf(cp), asp = fabsf(sp);
    float hwp = 0.5f * (wp * acp + hp * asp);
    float hhp = 0.5f * (wp * asp + hp * acp);
    float act = fabsf(ct), ast = fabsf(st);
    float hwt = 0.5f * (wt * act + ht * ast);
    float hht = 0.5f * (wt * ast + ht * act);

    float xmin = fminf(cxp - hwp, cxt - hwt);
    float xmax = fmaxf(cxp + hwp, cxt + hwt);
    float ymin = fminf(cyp - hhp, cyt - hht);
    float ymax = fmaxf(cyp + hhp, cyt + hht);

    float dxr = xmax - xmin;
    float dyr = ymax - ymin;
    const float inv_g = 1.0f / (float)GRID_G;
    float stepx = dxr * inv_g;

    const float K2 = K_SLOPE * LOG2E;
    float cwp = -0.5f * K2 * wp;
    float chp = -0.5f * K2 * hp;
    float cwt = -0.5f * K2 * wt;
    float cht = -0.5f * K2 * ht;

    float iw1 = stepx * cp, ih1 = -stepx * sp;
    float iw2 = stepx * ct, ih2 = -stepx * st;

    float px0 = fmaf(dxr, 0.5f * inv_g, xmin);
    float dxp = px0 - cxp, dxt = px0 - cxt;

    float s1 = 0.f, s2 = 0.f, s12 = 0.f;

    #pragma unroll
    for (int r = 0; r < GRID_G / 4; ++r) {
        int gy = sub * (GRID_G / 4) + r;
        float py  = fmaf(dyr, ((float)gy + 0.5f) * inv_g, ymin);
        float dyp = py - cyp, dyt = py - cyt;

        float rw1_0 =  dxp * cp + dyp * sp;
        float rh1_0 = -dxp * sp + dyp * cp;
        float rw2_0 =  dxt * ct + dyt * st;
        float rh2_0 = -dxt * st + dyt * ct;

        #pragma unroll
        for (int gx = 0; gx < GRID_G; ++gx) {
            float g = (float)gx;
            float rw1 = fmaf(g, iw1, rw1_0);
            float rh1 = fmaf(g, ih1, rh1_0);
            float rw2 = fmaf(g, iw2, rw2_0);
            float rh2 = fmaf(g, ih2, rh2_0);

            float ea1 = __builtin_amdgcn_exp2f(fmaf(K2, fabsf(rw1), cwp));
            float eb1 = __builtin_amdgcn_exp2f(fmaf(K2, fabsf(rh1), chp));
            float ea2 = __builtin_amdgcn_exp2f(fmaf(K2, fabsf(rw2), cwt));
            float eb2 = __builtin_amdgcn_exp2f(fmaf(K2, fabsf(rh2), cht));

            float d1 = (1.0f + ea1) * (1.0f + eb1);
            float d2 = (1.0f + ea2) * (1.0f + eb2);
            float r1 = __builtin_amdgcn_rcpf(d1);
            float r2 = __builtin_amdgcn_rcpf(d2);

            s1  += r1;
            s2  += r2;
            s12  = fmaf(r1, r2, s12);
        }
    }

    #pragma unroll
    for (int m = 1; m < 4; m <<= 1) {
        s1  += __shfl_xor(s1,  m);
        s2  += __shfl_xor(s2,  m);
        s12 += __shfl_xor(s12, m);
    }

    if (sub == 0)
        out[pair] = s12 / (s1 + s2 - s12 + 1e-6f);
}

extern "C" void kernel_launch(void* const* d_in, const int* in_sizes, int n_in,
                              void* d_out, int out_size, void* d_ws, size_t ws_size,
                              hipStream_t stream) {
    const float* P = (const float*)d_in[0];
    const float* T = (const float*)d_in[1];
    float* out = (float*)d_out;

    int N = in_sizes[0] / 5;
    int M = in_sizes[1] / 5;
    long long NM = (long long)N * M;

    size_t need = 16 + (size_t)NM * sizeof(unsigned int);
    if (ws_size < need) {
        // workspace too small: monolithic fallback
        long long total = NM * 4;
        int grid = (int)((total + 255) / 256);
        piou_pairwise_kernel<<<grid, 256, 0, stream>>>(P, T, out, N, M);
        return;
    }

    unsigned int* count = (unsigned int*)d_ws;
    unsigned int* list  = (unsigned int*)((char*)d_ws + 16);

    hipMemsetAsync(d_ws, 0, 16, stream);

    int grid1 = (int)((NM + 255) / 256);
    classify_kernel<<<grid1, 256, 0, stream>>>(P, T, out, count, list, N, M);
    piou_close_kernel<<<P2_BLOCKS, 256, 0, stream>>>(P, T, out, count, list, M);
}

// Round 5
// 35.623 us; speedup vs baseline: 1.6714x; 1.6714x over previous
//
#include <hip/hip_runtime.h>
#include <math.h>

#define GRID_G 16
#define K_SLOPE 10.0f
#define LOG2E 1.4426950408889634f
#define GAP2 (4.5f * 4.5f)   // AABB-gap^2 above which IoU <= 4e-6 (proven bound)
#define NBLOCKS 8192         // 32768 waves, grid-stride over pairs

__global__ __launch_bounds__(256) void piou_fused_kernel(
    const float* __restrict__ P,   // [N,5] cx,cy,w,h,theta
    const float* __restrict__ T,   // [M,5]
    float* __restrict__ out,       // [N,M]
    int N, int M)
{
    const int lane   = threadIdx.x & 63;
    const int wave   = (int)((blockIdx.x * 256u + threadIdx.x) >> 6);
    const int NM     = N * M;
    const int stride = NBLOCKS * 4;              // total waves in grid

    const float K2    = K_SLOPE * LOG2E;
    const float inv_g = 1.0f / (float)GRID_G;

    for (int pair = wave; pair < NM; pair += stride) {
        int i = pair / M, j = pair - i * M;

        // all 64 lanes load the same two box rows (HW broadcast, L1/L2-resident)
        float cxp = P[5*i+0], cyp = P[5*i+1], wp = P[5*i+2], hp = P[5*i+3], thp = P[5*i+4];
        float cxt = T[5*j+0], cyt = T[5*j+1], wt = T[5*j+2], ht = T[5*j+3], tht = T[5*j+4];

        float sp, cp, st, ct;
        __sincosf(thp, &sp, &cp);    // args in [-pi/2,pi/2]; err ~5e-7, IoU err <~1e-3
        __sincosf(tht, &st, &ct);

        float acp = fabsf(cp), asp = fabsf(sp);
        float hwp = 0.5f * (wp * acp + hp * asp);
        float hhp = 0.5f * (wp * asp + hp * acp);
        float act = fabsf(ct), ast = fabsf(st);
        float hwt = 0.5f * (wt * act + ht * ast);
        float hht = 0.5f * (wt * ast + ht * act);

        // wave-uniform classification (identical on all lanes -> s_cbranch skips body)
        float gapx = fmaxf(0.f, fabsf(cxp - cxt) - (hwp + hwt));
        float gapy = fmaxf(0.f, fabsf(cyp - cyt) - (hhp + hht));
        if (gapx * gapx + gapy * gapy > GAP2) {
            if (lane == 0) out[pair] = 0.0f;
            continue;
        }

        // ---- heavy path (~4% of pairs) ----
        float xmin = fminf(cxp - hwp, cxt - hwt);
        float xmax = fmaxf(cxp + hwp, cxt + hwt);
        float ymin = fminf(cyp - hhp, cyt - hht);
        float ymax = fmaxf(cyp + hhp, cyt + hht);

        float dxr = xmax - xmin, dyr = ymax - ymin;
        float stepx = dxr * inv_g, stepy = dyr * inv_g;

        float cwp = -0.5f * K2 * wp, chp = -0.5f * K2 * hp;
        float cwt = -0.5f * K2 * wt, cht = -0.5f * K2 * ht;

        float px0 = fmaf(dxr, 0.5f * inv_g, xmin);
        float py0 = fmaf(dyr, 0.5f * inv_g, ymin);
        float dx1 = px0 - cxp, dy1 = py0 - cyp;
        float dx2 = px0 - cxt, dy2 = py0 - cyt;

        // rotated coords at sample (gx=0,gy=0) + per-gx / per-gy increments
        float rw1_00 =  dx1*cp + dy1*sp,  iwx1 =  stepx*cp,  iwy1 = stepy*sp;
        float rh1_00 = -dx1*sp + dy1*cp,  ihx1 = -stepx*sp,  ihy1 = stepy*cp;
        float rw2_00 =  dx2*ct + dy2*st,  iwx2 =  stepx*ct,  iwy2 = stepy*st;
        float rh2_00 = -dx2*st + dy2*ct,  ihx2 = -stepx*st,  ihy2 = stepy*ct;

        float s1 = 0.f, s2 = 0.f, s12 = 0.f;

        #pragma unroll
        for (int q = 0; q < 4; ++q) {
            int s = lane + (q << 6);             // flattened sample id: gy*16+gx
            float fgx = (float)(s & 15);
            float fgy = (float)(s >> 4);

            float rw1 = fmaf(fgy, iwy1, fmaf(fgx, iwx1, rw1_00));
            float rh1 = fmaf(fgy, ihy1, fmaf(fgx, ihx1, rh1_00));
            float rw2 = fmaf(fgy, iwy2, fmaf(fgx, iwx2, rw2_00));
            float rh2 = fmaf(fgy, ihy2, fmaf(fgx, ihx2, rh2_00));

            float ea1 = __builtin_amdgcn_exp2f(fmaf(K2, fabsf(rw1), cwp));
            float eb1 = __builtin_amdgcn_exp2f(fmaf(K2, fabsf(rh1), chp));
            float ea2 = __builtin_amdgcn_exp2f(fmaf(K2, fabsf(rw2), cwt));
            float eb2 = __builtin_amdgcn_exp2f(fmaf(K2, fabsf(rh2), cht));

            // inf-safe: factors >= 1, rcp(inf)=0 gives exact F=0
            float r1 = __builtin_amdgcn_rcpf((1.0f + ea1) * (1.0f + eb1));
            float r2 = __builtin_amdgcn_rcpf((1.0f + ea2) * (1.0f + eb2));

            s1  += r1;
            s2  += r2;
            s12  = fmaf(r1, r2, s12);
        }

        // full-wave butterfly reduction (64 lanes)
        #pragma unroll
        for (int m = 1; m < 64; m <<= 1) {
            s1  += __shfl_xor(s1,  m);
            s2  += __shfl_xor(s2,  m);
            s12 += __shfl_xor(s12, m);
        }

        if (lane == 0)
            out[pair] = s12 / (s1 + s2 - s12 + 1e-6f);
    }
}

extern "C" void kernel_launch(void* const* d_in, const int* in_sizes, int n_in,
                              void* d_out, int out_size, void* d_ws, size_t ws_size,
                              hipStream_t stream) {
    const float* P = (const float*)d_in[0];
    const float* T = (const float*)d_in[1];
    float* out = (float*)d_out;

    int N = in_sizes[0] / 5;
    int M = in_sizes[1] / 5;

    piou_fused_kernel<<<NBLOCKS, 256, 0, stream>>>(P, T, out, N, M);
}

// Round 6
// 17.526 us; speedup vs baseline: 3.3973x; 2.0326x over previous
//
#include <hip/hip_runtime.h>
#include <math.h>

#define GRID_G 16
#define K_SLOPE 10.0f
#define LOG2E 1.4426950408889634f
#define GAP2 (4.5f * 4.5f)   // AABB-gap^2 above which IoU <= 4e-6 (proven bound)

__global__ __launch_bounds__(256) void piou_fused_kernel(
    const float* __restrict__ P,   // [N,5] cx,cy,w,h,theta
    const float* __restrict__ T,   // [M,5]
    float* __restrict__ out,       // [N,M]
    int N, int M)
{
    const int lane  = threadIdx.x & 63;
    const int chunk = (int)((blockIdx.x * 256u + threadIdx.x) >> 6);  // one 64-pair chunk per wave
    const int NM    = N * M;

    const float K2    = K_SLOPE * LOG2E;
    const float inv_g = 1.0f / (float)GRID_G;

    int pair = chunk * 64 + lane;          // this lane's pair
    bool valid = pair < NM;
    int pc = valid ? pair : 0;
    int i = pc / M;
    int j = pc - i * M;

    // ---- lane-parallel classification: 64 pairs per wave ----
    float cxp = P[5*i+0], cyp = P[5*i+1], wp = P[5*i+2], hp = P[5*i+3], thp = P[5*i+4];
    float cxt = T[5*j+0], cyt = T[5*j+1], wt = T[5*j+2], ht = T[5*j+3], tht = T[5*j+4];

    float sp, cp, st, ct;
    __sincosf(thp, &sp, &cp);    // args in [-pi/2,pi/2]; err ~1e-6 -> IoU err << threshold
    __sincosf(tht, &st, &ct);

    float hwp = 0.5f * (wp * fabsf(cp) + hp * fabsf(sp));
    float hhp = 0.5f * (wp * fabsf(sp) + hp * fabsf(cp));
    float hwt = 0.5f * (wt * fabsf(ct) + ht * fabsf(st));
    float hht = 0.5f * (wt * fabsf(st) + ht * fabsf(ct));

    float gapx = fmaxf(0.f, fabsf(cxp - cxt) - (hwp + hwt));
    float gapy = fmaxf(0.f, fabsf(cyp - cyt) - (hhp + hht));
    bool close = valid && (gapx * gapx + gapy * gapy <= GAP2);

    // far pairs: IoU <= 4e-6, emit 0 (coalesced masked store)
    if (valid && !close) out[pair] = 0.0f;

    unsigned long long mask = __ballot(close);

    // ---- wave-cooperative heavy path, one close pair at a time (~3 per wave avg) ----
    while (mask) {
        int l = __ffsll((long long)mask) - 1;
        mask &= mask - 1;

        // broadcast lane l's pair parameters (uniform index -> readlane)
        float bcp  = __shfl(cp,  l), bsp  = __shfl(sp,  l);
        float bct  = __shfl(ct,  l), bst  = __shfl(st,  l);
        float bcxp = __shfl(cxp, l), bcyp = __shfl(cyp, l);
        float bcxt = __shfl(cxt, l), bcyt = __shfl(cyt, l);
        float bwp  = __shfl(wp,  l), bhp  = __shfl(hp,  l);
        float bwt  = __shfl(wt,  l), bht  = __shfl(ht,  l);
        float bhwp = __shfl(hwp, l), bhhp = __shfl(hhp, l);
        float bhwt = __shfl(hwt, l), bhht = __shfl(hht, l);
        int bpair = chunk * 64 + l;

        float xmin = fminf(bcxp - bhwp, bcxt - bhwt);
        float xmax = fmaxf(bcxp + bhwp, bcxt + bhwt);
        float ymin = fminf(bcyp - bhhp, bcyt - bhht);
        float ymax = fmaxf(bcyp + bhhp, bcyt + bhht);

        float dxr = xmax - xmin, dyr = ymax - ymin;
        float stepx = dxr * inv_g, stepy = dyr * inv_g;

        float cwp = -0.5f * K2 * bwp, chp = -0.5f * K2 * bhp;
        float cwt = -0.5f * K2 * bwt, cht = -0.5f * K2 * bht;

        float px0 = fmaf(dxr, 0.5f * inv_g, xmin);
        float py0 = fmaf(dyr, 0.5f * inv_g, ymin);
        float dx1 = px0 - bcxp, dy1 = py0 - bcyp;
        float dx2 = px0 - bcxt, dy2 = py0 - bcyt;

        // rotated coords at (gx=0,gy=0) + per-gx / per-gy increments
        float rw1_00 =  dx1*bcp + dy1*bsp,  iwx1 =  stepx*bcp,  iwy1 = stepy*bsp;
        float rh1_00 = -dx1*bsp + dy1*bcp,  ihx1 = -stepx*bsp,  ihy1 = stepy*bcp;
        float rw2_00 =  dx2*bct + dy2*bst,  iwx2 =  stepx*bct,  iwy2 = stepy*bst;
        float rh2_00 = -dx2*bst + dy2*bct,  ihx2 = -stepx*bst,  ihy2 = stepy*bct;

        float s1 = 0.f, s2 = 0.f, s12 = 0.f;

        #pragma unroll
        for (int q = 0; q < 4; ++q) {
            int s = lane + (q << 6);             // flattened sample id: gy*16+gx
            float fgx = (float)(s & 15);
            float fgy = (float)(s >> 4);

            float rw1 = fmaf(fgy, iwy1, fmaf(fgx, iwx1, rw1_00));
            float rh1 = fmaf(fgy, ihy1, fmaf(fgx, ihx1, rh1_00));
            float rw2 = fmaf(fgy, iwy2, fmaf(fgx, iwx2, rw2_00));
            float rh2 = fmaf(fgy, ihy2, fmaf(fgx, ihx2, rh2_00));

            float ea1 = __builtin_amdgcn_exp2f(fmaf(K2, fabsf(rw1), cwp));
            float eb1 = __builtin_amdgcn_exp2f(fmaf(K2, fabsf(rh1), chp));
            float ea2 = __builtin_amdgcn_exp2f(fmaf(K2, fabsf(rw2), cwt));
            float eb2 = __builtin_amdgcn_exp2f(fmaf(K2, fabsf(rh2), cht));

            // inf-safe: factors >= 1, rcp(inf)=0 gives exact F=0
            float r1 = __builtin_amdgcn_rcpf((1.0f + ea1) * (1.0f + eb1));
            float r2 = __builtin_amdgcn_rcpf((1.0f + ea2) * (1.0f + eb2));

            s1  += r1;
            s2  += r2;
            s12  = fmaf(r1, r2, s12);
        }

        // full-wave butterfly reduction (64 lanes)
        #pragma unroll
        for (int m = 1; m < 64; m <<= 1) {
            s1  += __shfl_xor(s1,  m);
            s2  += __shfl_xor(s2,  m);
            s12 += __shfl_xor(s12, m);
        }

        if (lane == 0)
            out[bpair] = s12 / (s1 + s2 - s12 + 1e-6f);
    }
}

extern "C" void kernel_launch(void* const* d_in, const int* in_sizes, int n_in,
                              void* d_out, int out_size, void* d_ws, size_t ws_size,
                              hipStream_t stream) {
    const float* P = (const float*)d_in[0];
    const float* T = (const float*)d_in[1];
    float* out = (float*)d_out;

    int N = in_sizes[0] / 5;
    int M = in_sizes[1] / 5;
    long long NM = (long long)N * M;

    long long nwaves = (NM + 63) / 64;          // one 64-pair chunk per wave
    int nblocks = (int)((nwaves + 3) / 4);      // 4 waves per 256-thread block
    piou_fused_kernel<<<nblocks, 256, 0, stream>>>(P, T, out, N, M);
}

// Round 7
// 12.443 us; speedup vs baseline: 4.7853x; 1.4085x over previous
//
#include <hip/hip_runtime.h>
#include <math.h>

#define GRID_G 16
#define K_SLOPE 10.0f
#define LOG2E 1.4426950408889634f
#define GAP2 (4.5f * 4.5f)   // AABB-gap^2 above which IoU <= 4e-6 (proven bound)
#define ESTR 20              // floats per LDS queue entry (16 consts + id, padded to 80B)

__global__ __launch_bounds__(256) void piou_fused_kernel(
    const float* __restrict__ P,   // [N,5] cx,cy,w,h,theta
    const float* __restrict__ T,   // [M,5]
    float* __restrict__ out,       // [N,M]
    int N, int M)
{
    __shared__ __align__(16) float q[256 * ESTR];   // close-pair work queue
    __shared__ unsigned int wcnt[4];

    const int tid  = threadIdx.x;
    const int lane = tid & 63;
    const int w    = tid >> 6;
    const int NM   = N * M;

    const float K2    = K_SLOPE * LOG2E;
    const float inv_g = 1.0f / (float)GRID_G;

    // ---- phase 1: lane-parallel classify + per-pair setup (1 pair per thread) ----
    int pair = blockIdx.x * 256 + tid;
    bool valid = pair < NM;
    int pc = valid ? pair : 0;
    int i = pc / M;
    int j = pc - i * M;

    float cxp = P[5*i+0], cyp = P[5*i+1], wp = P[5*i+2], hp = P[5*i+3], thp = P[5*i+4];
    float cxt = T[5*j+0], cyt = T[5*j+1], wt = T[5*j+2], ht = T[5*j+3], tht = T[5*j+4];

    float sp, cp, st, ct;
    __sincosf(thp, &sp, &cp);    // args in [-pi/2,pi/2]; err ~1e-6 -> IoU err << threshold
    __sincosf(tht, &st, &ct);

    float hwp = 0.5f * (wp * fabsf(cp) + hp * fabsf(sp));
    float hhp = 0.5f * (wp * fabsf(sp) + hp * fabsf(cp));
    float hwt = 0.5f * (wt * fabsf(ct) + ht * fabsf(st));
    float hht = 0.5f * (wt * fabsf(st) + ht * fabsf(ct));

    float gapx = fmaxf(0.f, fabsf(cxp - cxt) - (hwp + hwt));
    float gapy = fmaxf(0.f, fabsf(cyp - cyt) - (hhp + hht));
    bool close = valid && (gapx * gapx + gapy * gapy <= GAP2);

    if (valid && !close) out[pair] = 0.0f;   // far: IoU <= 4e-6, exact-enough 0

    // per-pair heavy-loop constants (cheap; computed unconditionally, lane-parallel)
    float xmin = fminf(cxp - hwp, cxt - hwt);
    float xmax = fmaxf(cxp + hwp, cxt + hwt);
    float ymin = fminf(cyp - hhp, cyt - hht);
    float ymax = fmaxf(cyp + hhp, cyt + hht);
    float dxr = xmax - xmin, dyr = ymax - ymin;
    float stepx = dxr * inv_g, stepy = dyr * inv_g;
    float px0 = fmaf(dxr, 0.5f * inv_g, xmin);
    float py0 = fmaf(dyr, 0.5f * inv_g, ymin);
    float dx1 = px0 - cxp, dy1 = py0 - cyp;
    float dx2 = px0 - cxt, dy2 = py0 - cyt;

    float rw1_00 =  dx1*cp + dy1*sp,  iwx1 =  stepx*cp,  iwy1 = stepy*sp;
    float rh1_00 = -dx1*sp + dy1*cp,  ihx1 = -stepx*sp,  ihy1 = stepy*cp;
    float rw2_00 =  dx2*ct + dy2*st,  iwx2 =  stepx*ct,  iwy2 = stepy*st;
    float rh2_00 = -dx2*st + dy2*ct,  ihx2 = -stepx*st,  ihy2 = stepy*ct;
    float cwp = -0.5f * K2 * wp, chp = -0.5f * K2 * hp;
    float cwt = -0.5f * K2 * wt, cht = -0.5f * K2 * ht;

    // ---- block-level compaction into LDS queue (no atomics) ----
    unsigned long long mask = __ballot(close);
    unsigned int myoff = (unsigned int)__popcll(mask & ((1ull << lane) - 1ull));
    if (lane == 0) wcnt[w] = (unsigned int)__popcll(mask);
    __syncthreads();

    unsigned int base = 0;
    #pragma unroll
    for (int u = 0; u < 4; ++u) base += (u < w) ? wcnt[u] : 0u;
    unsigned int C = wcnt[0] + wcnt[1] + wcnt[2] + wcnt[3];

    if (close) {
        float* e = &q[(base + myoff) * ESTR];
        ((float4*)e)[0] = make_float4(rw1_00, rh1_00, rw2_00, rh2_00);
        ((float4*)e)[1] = make_float4(iwx1,   ihx1,   iwx2,   ihx2);
        ((float4*)e)[2] = make_float4(iwy1,   ihy1,   iwy2,   ihy2);
        ((float4*)e)[3] = make_float4(cwp,    chp,    cwt,    cht);
        e[16] = __int_as_float(pair);
    }
    __syncthreads();

    // ---- phase 2: heavy path, 16 lanes per pair, 16 pairs per block-iteration ----
    const int g  = tid >> 4;    // group id 0..15
    const int lx = tid & 15;    // lane within group = gx column
    const float fgx = (float)lx;

    for (unsigned int e = g; e < C; e += 16) {
        const float* p = &q[e * ESTR];
        float4 A  = ((const float4*)p)[0];   // rw1_00, rh1_00, rw2_00, rh2_00
        float4 Bx = ((const float4*)p)[1];   // iwx1, ihx1, iwx2, ihx2
        float4 By = ((const float4*)p)[2];   // iwy1, ihy1, iwy2, ihy2
        float4 Cc = ((const float4*)p)[3];   // cwp, chp, cwt, cht
        int bpair = __float_as_int(p[16]);

        // this lane's gx-column base
        float brw1 = fmaf(fgx, Bx.x, A.x);
        float brh1 = fmaf(fgx, Bx.y, A.y);
        float brw2 = fmaf(fgx, Bx.z, A.z);
        float brh2 = fmaf(fgx, Bx.w, A.w);

        float s1 = 0.f, s2 = 0.f, s12 = 0.f;

        #pragma unroll
        for (int gy = 0; gy < GRID_G; ++gy) {
            float fgy = (float)gy;
            float rw1 = fmaf(fgy, By.x, brw1);
            float rh1 = fmaf(fgy, By.y, brh1);
            float rw2 = fmaf(fgy, By.z, brw2);
            float rh2 = fmaf(fgy, By.w, brh2);

            float ea1 = __builtin_amdgcn_exp2f(fmaf(K2, fabsf(rw1), Cc.x));
            float eb1 = __builtin_amdgcn_exp2f(fmaf(K2, fabsf(rh1), Cc.y));
            float ea2 = __builtin_amdgcn_exp2f(fmaf(K2, fabsf(rw2), Cc.z));
            float eb2 = __builtin_amdgcn_exp2f(fmaf(K2, fabsf(rh2), Cc.w));

            // inf-safe: factors >= 1, rcp(inf)=0 gives exact F=0
            float r1 = __builtin_amdgcn_rcpf((1.0f + ea1) * (1.0f + eb1));
            float r2 = __builtin_amdgcn_rcpf((1.0f + ea2) * (1.0f + eb2));

            s1  += r1;
            s2  += r2;
            s12  = fmaf(r1, r2, s12);
        }

        // 16-lane butterfly (xor masks 1,2,4,8 stay within the aligned group)
        #pragma unroll
        for (int m = 1; m < 16; m <<= 1) {
            s1  += __shfl_xor(s1,  m);
            s2  += __shfl_xor(s2,  m);
            s12 += __shfl_xor(s12, m);
        }

        if (lx == 0)
            out[bpair] = s12 / (s1 + s2 - s12 + 1e-6f);
    }
}

extern "C" void kernel_launch(void* const* d_in, const int* in_sizes, int n_in,
                              void* d_out, int out_size, void* d_ws, size_t ws_size,
                              hipStream_t stream) {
    const float* P = (const float*)d_in[0];
    const float* T = (const float*)d_in[1];
    float* out = (float*)d_out;

    int N = in_sizes[0] / 5;
    int M = in_sizes[1] / 5;
    long long NM = (long long)N * M;

    int nblocks = (int)((NM + 255) / 256);   // 256 pairs per block
    piou_fused_kernel<<<nblocks, 256, 0, stream>>>(P, T, out, N, M);
}